// Round 2
// baseline (152.134 us; speedup 1.0000x reference)
//
#include <hip/hip_runtime.h>

// Problem constants: B=16, C=3, H=W=512.
// priority(b,y,x) = min(eye+mouth, 1), eye = clip(1 - sqrt(min d2 over pts36..47)/15, 0, 1),
// mouth same over pts 48..67.  weight = 1 + 299*priority.  out = mean(|pred-target|*weight).
//
// Single-kernel version: per-block partials -> last-block-standing final reduce
// (deterministic tree sum, no float atomics). Counter lives in d_ws and is
// zeroed by a capturable 4-byte hipMemsetAsync each call.

constexpr int   kW        = 512;
constexpr int   kHW       = 512 * 512;     // pixels per (b,c) plane
constexpr int   kG        = kHW / 4;       // float4 groups per plane = 65536
constexpr int   kBlocksX  = 64;
constexpr int   kThreads  = 256;
constexpr int   kBlocks   = kBlocksX * 16; // 1024 total blocks
constexpr int   kIters    = kG / (kBlocksX * kThreads);   // 4
constexpr float kInvR     = 1.0f / 15.0f;
constexpr float kInvN     = 1.0f / (16.0f * 3.0f * 512.0f * 512.0f);

__device__ __forceinline__ float clamp01(float v) {
    return fminf(fmaxf(v, 0.0f), 1.0f);
}

__global__ __launch_bounds__(kThreads) void eml_fused(
        const float* __restrict__ pred,
        const float* __restrict__ target,
        const int*   __restrict__ lm,       // (16, 68, 2) int32
        float*       __restrict__ partial,  // kBlocks floats (d_ws + 0)
        unsigned int* __restrict__ counter, // 1 uint (d_ws + 4096), zeroed per call
        float*       __restrict__ out)
{
    __shared__ float s_cx[32], s_cy[32];
    const int b   = blockIdx.y;
    const int tid = threadIdx.x;

    if (tid < 32) {
        const int j  = 36 + tid;                 // points 36..67
        int xi = lm[b * 136 + j * 2 + 0];
        int yi = lm[b * 136 + j * 2 + 1];
        xi = min(max(xi, 0), kW - 1);
        yi = min(max(yi, 0), kW - 1);
        s_cx[tid] = (float)xi;
        s_cy[tid] = (float)yi;
    }
    __syncthreads();

    const float4* __restrict__ pred4 = (const float4*)pred   + (size_t)b * 3 * kG;
    const float4* __restrict__ tgt4  = (const float4*)target + (size_t)b * 3 * kG;

    float acc = 0.0f;

    for (int it = 0; it < kIters; ++it) {
        const int g  = it * (kBlocksX * kThreads) + blockIdx.x * kThreads + tid;
        const int x4 = (g & 127) << 2;           // x of first pixel in the float4
        const float y  = (float)(g >> 7);
        const float x0 = (float)x4;
        const float x1 = x0 + 1.0f, x2 = x0 + 2.0f, x3 = x0 + 3.0f;

        float de0 = 1e30f, de1 = 1e30f, de2 = 1e30f, de3 = 1e30f;  // eye min d^2
        float dm0 = 1e30f, dm1 = 1e30f, dm2 = 1e30f, dm3 = 1e30f;  // mouth min d^2

#pragma unroll
        for (int j = 0; j < 12; ++j) {           // eye points
            const float dy  = y - s_cy[j];
            const float dy2 = dy * dy;
            float dx;
            dx = x0 - s_cx[j]; de0 = fminf(de0, fmaf(dx, dx, dy2));
            dx = x1 - s_cx[j]; de1 = fminf(de1, fmaf(dx, dx, dy2));
            dx = x2 - s_cx[j]; de2 = fminf(de2, fmaf(dx, dx, dy2));
            dx = x3 - s_cx[j]; de3 = fminf(de3, fmaf(dx, dx, dy2));
        }
#pragma unroll
        for (int j = 12; j < 32; ++j) {          // mouth points
            const float dy  = y - s_cy[j];
            const float dy2 = dy * dy;
            float dx;
            dx = x0 - s_cx[j]; dm0 = fminf(dm0, fmaf(dx, dx, dy2));
            dx = x1 - s_cx[j]; dm1 = fminf(dm1, fmaf(dx, dx, dy2));
            dx = x2 - s_cx[j]; dm2 = fminf(dm2, fmaf(dx, dx, dy2));
            dx = x3 - s_cx[j]; dm3 = fminf(dm3, fmaf(dx, dx, dy2));
        }

        const float e0 = clamp01(1.0f - sqrtf(de0) * kInvR);
        const float e1 = clamp01(1.0f - sqrtf(de1) * kInvR);
        const float e2 = clamp01(1.0f - sqrtf(de2) * kInvR);
        const float e3 = clamp01(1.0f - sqrtf(de3) * kInvR);
        const float m0 = clamp01(1.0f - sqrtf(dm0) * kInvR);
        const float m1 = clamp01(1.0f - sqrtf(dm1) * kInvR);
        const float m2 = clamp01(1.0f - sqrtf(dm2) * kInvR);
        const float m3 = clamp01(1.0f - sqrtf(dm3) * kInvR);

        const float w0 = fmaf(299.0f, fminf(e0 + m0, 1.0f), 1.0f);
        const float w1 = fmaf(299.0f, fminf(e1 + m1, 1.0f), 1.0f);
        const float w2 = fmaf(299.0f, fminf(e2 + m2, 1.0f), 1.0f);
        const float w3 = fmaf(299.0f, fminf(e3 + m3, 1.0f), 1.0f);

#pragma unroll
        for (int c = 0; c < 3; ++c) {
            const float4 p = pred4[c * kG + g];
            const float4 t = tgt4[c * kG + g];
            acc = fmaf(fabsf(p.x - t.x), w0, acc);
            acc = fmaf(fabsf(p.y - t.y), w1, acc);
            acc = fmaf(fabsf(p.z - t.z), w2, acc);
            acc = fmaf(fabsf(p.w - t.w), w3, acc);
        }
    }

    // wave (64-lane) shuffle reduction
#pragma unroll
    for (int off = 32; off > 0; off >>= 1)
        acc += __shfl_down(acc, off, 64);

    __shared__ float s_wsum[4];
    const int lane = tid & 63;
    const int wid  = tid >> 6;
    if (lane == 0) s_wsum[wid] = acc;
    __syncthreads();

    __shared__ bool s_last;
    if (tid == 0) {
        const int bid = b * kBlocksX + blockIdx.x;
        partial[bid] = s_wsum[0] + s_wsum[1] + s_wsum[2] + s_wsum[3];
        __threadfence();                              // publish partial (device scope)
        const unsigned int prev = atomicAdd(counter, 1u);
        s_last = (prev == (unsigned int)(kBlocks - 1));
    }
    __syncthreads();

    if (s_last) {
        // last block standing: deterministic final reduce of kBlocks partials
        __threadfence();                              // acquire others' partials
        float v = partial[tid] + partial[tid + 256] + partial[tid + 512] + partial[tid + 768];
#pragma unroll
        for (int off = 32; off > 0; off >>= 1)
            v += __shfl_down(v, off, 64);
        if (lane == 0) s_wsum[wid] = v;
        __syncthreads();
        if (tid == 0)
            out[0] = (s_wsum[0] + s_wsum[1] + s_wsum[2] + s_wsum[3]) * kInvN;
    }
}

extern "C" void kernel_launch(void* const* d_in, const int* in_sizes, int n_in,
                              void* d_out, int out_size, void* d_ws, size_t ws_size,
                              hipStream_t stream) {
    const float* pred   = (const float*)d_in[0];
    const float* target = (const float*)d_in[1];
    const int*   lm     = (const int*)d_in[2];
    float*        out     = (float*)d_out;
    float*        partial = (float*)d_ws;                      // 4 KiB
    unsigned int* counter = (unsigned int*)((char*)d_ws + 4096);

    // zero only the 4-byte arrival counter (capturable async memset)
    hipMemsetAsync(counter, 0, sizeof(unsigned int), stream);

    dim3 grid(kBlocksX, 16);
    eml_fused<<<grid, kThreads, 0, stream>>>(pred, target, lm, partial, counter, out);
}

// Round 3
// 115.736 us; speedup vs baseline: 1.3145x; 1.3145x over previous
//
#include <hip/hip_runtime.h>

// Problem constants: B=16, C=3, H=W=512.
// priority(b,y,x) = min(eye+mouth, 1), eye = clip(1 - sqrt(min d2 over pts36..47)/15, 0, 1),
// mouth same over pts 48..67.  weight = 1 + 299*priority.  out = mean(|pred-target|*weight).
//
// Latency-hiding structure: 1 pixel-group (float4 of x) per thread, all 6
// global loads issued BEFORE the ~450-op distance compute so the memory
// round-trip overlaps ALU work. Two-kernel deterministic reduction.

constexpr int   kW        = 512;
constexpr int   kG        = 512 * 512 / 4;  // float4 groups per plane = 65536
constexpr int   kThreads  = 256;
constexpr int   kBlocksX  = kG / kThreads;  // 256 blocks per batch
constexpr int   kBlocks   = kBlocksX * 16;  // 4096 total
constexpr float kInvR     = 1.0f / 15.0f;
constexpr float kInvN     = 1.0f / (16.0f * 3.0f * 512.0f * 512.0f);

__device__ __forceinline__ float clamp01(float v) {
    return fminf(fmaxf(v, 0.0f), 1.0f);
}

__global__ __launch_bounds__(kThreads) void eml_main(
        const float* __restrict__ pred,
        const float* __restrict__ target,
        const int*   __restrict__ lm,      // (16, 68, 2) int32
        float*       __restrict__ partial) // kBlocks floats
{
    __shared__ float s_cx[32], s_cy[32];
    const int b   = blockIdx.y;
    const int tid = threadIdx.x;

    if (tid < 32) {
        const int j  = 36 + tid;                 // points 36..67
        int xi = lm[b * 136 + j * 2 + 0];
        int yi = lm[b * 136 + j * 2 + 1];
        xi = min(max(xi, 0), kW - 1);
        yi = min(max(yi, 0), kW - 1);
        s_cx[tid] = (float)xi;
        s_cy[tid] = (float)yi;
    }
    __syncthreads();

    const int g = blockIdx.x * kThreads + tid;   // position within batch plane

    const float4* __restrict__ pred4 = (const float4*)pred   + (size_t)b * 3 * kG;
    const float4* __restrict__ tgt4  = (const float4*)target + (size_t)b * 3 * kG;

    // ---- issue ALL global loads first; latency hides behind distance compute
    const float4 p0 = pred4[0 * kG + g];
    const float4 p1 = pred4[1 * kG + g];
    const float4 p2 = pred4[2 * kG + g];
    const float4 t0 = tgt4[0 * kG + g];
    const float4 t1 = tgt4[1 * kG + g];
    const float4 t2 = tgt4[2 * kG + g];

    // ---- distance / weight compute (~450 VALU ops, independent of loads)
    const float y  = (float)(g >> 7);
    const float x0 = (float)((g & 127) << 2);
    const float x1 = x0 + 1.0f, x2 = x0 + 2.0f, x3 = x0 + 3.0f;

    float de0 = 1e30f, de1 = 1e30f, de2 = 1e30f, de3 = 1e30f;  // eye min d^2
    float dm0 = 1e30f, dm1 = 1e30f, dm2 = 1e30f, dm3 = 1e30f;  // mouth min d^2

#pragma unroll
    for (int j = 0; j < 12; ++j) {               // eye points
        const float dy  = y - s_cy[j];
        const float dy2 = dy * dy;
        float dx;
        dx = x0 - s_cx[j]; de0 = fminf(de0, fmaf(dx, dx, dy2));
        dx = x1 - s_cx[j]; de1 = fminf(de1, fmaf(dx, dx, dy2));
        dx = x2 - s_cx[j]; de2 = fminf(de2, fmaf(dx, dx, dy2));
        dx = x3 - s_cx[j]; de3 = fminf(de3, fmaf(dx, dx, dy2));
    }
#pragma unroll
    for (int j = 12; j < 32; ++j) {              // mouth points
        const float dy  = y - s_cy[j];
        const float dy2 = dy * dy;
        float dx;
        dx = x0 - s_cx[j]; dm0 = fminf(dm0, fmaf(dx, dx, dy2));
        dx = x1 - s_cx[j]; dm1 = fminf(dm1, fmaf(dx, dx, dy2));
        dx = x2 - s_cx[j]; dm2 = fminf(dm2, fmaf(dx, dx, dy2));
        dx = x3 - s_cx[j]; dm3 = fminf(dm3, fmaf(dx, dx, dy2));
    }

    const float e0 = clamp01(1.0f - sqrtf(de0) * kInvR);
    const float e1 = clamp01(1.0f - sqrtf(de1) * kInvR);
    const float e2 = clamp01(1.0f - sqrtf(de2) * kInvR);
    const float e3 = clamp01(1.0f - sqrtf(de3) * kInvR);
    const float m0 = clamp01(1.0f - sqrtf(dm0) * kInvR);
    const float m1 = clamp01(1.0f - sqrtf(dm1) * kInvR);
    const float m2 = clamp01(1.0f - sqrtf(dm2) * kInvR);
    const float m3 = clamp01(1.0f - sqrtf(dm3) * kInvR);

    const float w0 = fmaf(299.0f, fminf(e0 + m0, 1.0f), 1.0f);
    const float w1 = fmaf(299.0f, fminf(e1 + m1, 1.0f), 1.0f);
    const float w2 = fmaf(299.0f, fminf(e2 + m2, 1.0f), 1.0f);
    const float w3 = fmaf(299.0f, fminf(e3 + m3, 1.0f), 1.0f);

    // ---- consume loads (2 independent accumulator chains, merged at end)
    float accA = 0.0f, accB = 0.0f;
    accA = fmaf(fabsf(p0.x - t0.x), w0, accA);
    accB = fmaf(fabsf(p0.y - t0.y), w1, accB);
    accA = fmaf(fabsf(p0.z - t0.z), w2, accA);
    accB = fmaf(fabsf(p0.w - t0.w), w3, accB);
    accA = fmaf(fabsf(p1.x - t1.x), w0, accA);
    accB = fmaf(fabsf(p1.y - t1.y), w1, accB);
    accA = fmaf(fabsf(p1.z - t1.z), w2, accA);
    accB = fmaf(fabsf(p1.w - t1.w), w3, accB);
    accA = fmaf(fabsf(p2.x - t2.x), w0, accA);
    accB = fmaf(fabsf(p2.y - t2.y), w1, accB);
    accA = fmaf(fabsf(p2.z - t2.z), w2, accA);
    accB = fmaf(fabsf(p2.w - t2.w), w3, accB);
    float acc = accA + accB;

    // wave (64-lane) shuffle reduction
#pragma unroll
    for (int off = 32; off > 0; off >>= 1)
        acc += __shfl_down(acc, off, 64);

    __shared__ float s_wsum[4];
    const int lane = tid & 63;
    const int wid  = tid >> 6;
    if (lane == 0) s_wsum[wid] = acc;
    __syncthreads();
    if (tid == 0)
        partial[b * kBlocksX + blockIdx.x] = s_wsum[0] + s_wsum[1] + s_wsum[2] + s_wsum[3];
}

__global__ __launch_bounds__(256) void eml_finish(
        const float* __restrict__ partial,   // kBlocks = 4096 floats
        float*       __restrict__ out)
{
    const int tid = threadIdx.x;
    float v = 0.0f;
#pragma unroll
    for (int k = 0; k < kBlocks / 256; ++k)      // 16 strided reads
        v += partial[tid + k * 256];
#pragma unroll
    for (int off = 32; off > 0; off >>= 1)
        v += __shfl_down(v, off, 64);

    __shared__ float s_wsum[4];
    if ((tid & 63) == 0) s_wsum[tid >> 6] = v;
    __syncthreads();
    if (tid == 0)
        out[0] = (s_wsum[0] + s_wsum[1] + s_wsum[2] + s_wsum[3]) * kInvN;
}

extern "C" void kernel_launch(void* const* d_in, const int* in_sizes, int n_in,
                              void* d_out, int out_size, void* d_ws, size_t ws_size,
                              hipStream_t stream) {
    const float* pred   = (const float*)d_in[0];
    const float* target = (const float*)d_in[1];
    const int*   lm     = (const int*)d_in[2];
    float* out     = (float*)d_out;
    float* partial = (float*)d_ws;               // 16 KiB

    dim3 grid(kBlocksX, 16);
    eml_main<<<grid, kThreads, 0, stream>>>(pred, target, lm, partial);
    eml_finish<<<1, 256, 0, stream>>>(partial, out);
}